// Round 8
// baseline (205.691 us; speedup 1.0000x reference)
//
#include <hip/hip_runtime.h>

typedef float f4 __attribute__((ext_vector_type(4)));
typedef float f16v __attribute__((ext_vector_type(16)));
typedef _Float16 hf;
typedef __fp16 fp16x2 __attribute__((ext_vector_type(2)));
typedef hf h8 __attribute__((ext_vector_type(8)));
typedef unsigned short ushort_t;
typedef unsigned int uint_t;
typedef uint_t u4 __attribute__((ext_vector_type(4)));

#define BATCH 8
#define CH 128
#define NPIX 4096
#define LOG2E 1.4426950408889634f
#define RESCALE_THR 8.0f  // defer-max threshold (base-2 units); P bounded by 2^8

__device__ inline f16v mfma32h(h8 a, h8 b, f16v c) {
    return __builtin_amdgcn_mfma_f32_32x32x16_f16(a, b, c, 0, 0, 0);
}

__device__ inline uint_t pk2h(float a, float b) {  // pack 2 fp32 -> fp16x2 (RTZ), as u32
    fp16x2 pp = __builtin_amdgcn_cvt_pkrtz(a, b);
    union { fp16x2 v; uint_t u; } cv;
    cv.v = pp;
    return cv.u;
}

// after: a = {a_lo31, b_lo31}, b = {a_hi31, b_hi31}
__device__ inline void pl32swap(uint_t& a, uint_t& b) {
    asm("v_permlane32_swap_b32 %0, %1" : "+v"(a), "+v"(b));
}

typedef __attribute__((address_space(3))) uint_t lds_uint;
typedef __attribute__((address_space(1))) const uint_t global_uint;
__device__ inline void dma16(const void* g, void* l) {
    __builtin_amdgcn_global_load_lds((global_uint*)g, (lds_uint*)l, 16, 0, 0);
}

__device__ inline ushort_t h2u(hf x) {
    union { hf h; ushort_t u; } cv;
    cv.h = x;
    return cv.u;
}

// wait(own oldest DMAs) -> barrier -> pin schedule
#define WAITB(vm)                                                          \
    do {                                                                   \
        asm volatile("s_waitcnt vmcnt(" #vm ") lgkmcnt(0)" ::: "memory");  \
        __builtin_amdgcn_s_barrier();                                      \
        __builtin_amdgcn_sched_barrier(0);                                 \
    } while (0)

// plain barrier (no vmcnt drain): frees LDS buffer for next stage
#define BARB()                              \
    do {                                    \
        __builtin_amdgcn_s_barrier();       \
        __builtin_amdgcn_sched_barrier(0);  \
    } while (0)

// ---------------- QKV projection via MFMA (fp16 hi/lo 2-pass) ----------------
// X converted to fp16 hi/lo ONCE into LDS; fragments via ds_read_b128.
// Q: [b][n][c] (log2e-scaled);  K: [b][n][c];  V: [b][c][n].  All fp16.
__global__ __launch_bounds__(256) void qkv_kernel(const float* __restrict__ x1,
                                                  const float* __restrict__ x2,
                                                  const float* __restrict__ Wq,
                                                  const float* __restrict__ Wk,
                                                  const float* __restrict__ Wv,
                                                  const float* __restrict__ bq,
                                                  const float* __restrict__ bk,
                                                  const float* __restrict__ bv,
                                                  hf* __restrict__ Qf, hf* __restrict__ Kf,
                                                  hf* __restrict__ Vf) {
    // XH/XL[n][c] fp16, 64 x 128, rows 256B = 16 slots of 16B; slot s stored at
    // s' = s ^ (n&15)  -> conflict-free b128 reads.
    __shared__ __align__(16) ushort_t XH[64 * 128];
    __shared__ __align__(16) ushort_t XL[64 * 128];

    int bid = blockIdx.x;
    int m = bid >> 9;          // 0:Q 1:K 2:V
    int rem = bid & 511;
    int b = rem & 7;
    int n0 = (rem >> 3) << 6;  // 64-px chunk

    const float* X = ((m == 0) ? x1 : x2) + (size_t)b * CH * NPIX;
    const float* bias = (m == 0) ? bq : (m == 1) ? bk : bv;

    int tid = threadIdx.x;
    // stage X fp32 -> cvt hi/lo fp16 -> LDS [n][c] swizzled (coalesced global reads)
#pragma unroll
    for (int r = 0; r < 8; ++r) {
        int c = 16 * r + (tid >> 4);
        int n4 = (tid & 15) << 2;
        f4 v = *(const f4*)&X[(size_t)c * NPIX + n0 + n4];
        int cs = c >> 3, cj = c & 7;
#pragma unroll
        for (int j = 0; j < 4; ++j) {
            int n = n4 + j;
            hf hi = (hf)v[j];
            hf lo = (hf)(v[j] - (float)hi);
            int ofs = n * 128 + ((cs ^ (n & 15)) << 3) + cj;
            XH[ofs] = h2u(hi);
            XL[ofs] = h2u(lo);
        }
    }

    int lane = tid & 63;
    int w = tid >> 6;
    int h = lane >> 5;
    int m32 = lane & 31;
    int o0 = w * 32;  // this wave's 32 output channels

    // W fragments: read fp32 row o0+m32 of W directly, convert in-reg (same element
    // set serves as A-frag (V path) and B-frag (Q/K path)).
    const float* Wsrc = (m == 0) ? Wq : (m == 1) ? Wk : Wv;
    float wscale = (m == 0) ? LOG2E : 1.0f;
    h8 wf[8];
    {
        const float* wrow = Wsrc + (size_t)(o0 + m32) * CH;
#pragma unroll
        for (int kc = 0; kc < 8; ++kc) {
            f4 a = *(const f4*)&wrow[kc * 16 + h * 8];
            f4 b2 = *(const f4*)&wrow[kc * 16 + h * 8 + 4];
            h8 t;
#pragma unroll
            for (int j = 0; j < 4; ++j) {
                t[j] = (hf)(a[j] * wscale);
                t[4 + j] = (hf)(b2[j] * wscale);
            }
            wf[kc] = t;
        }
    }

    __syncthreads();

    f16v acc[2];
#pragma unroll
    for (int g = 0; g < 2; ++g)
#pragma unroll
        for (int r = 0; r < 16; ++r) acc[g][r] = 0.f;

    int swzn = m32 & 15;  // n&15 for n = g*32+m32
#pragma unroll
    for (int g = 0; g < 2; ++g) {
        int nrow = (g * 32 + m32) * 128;
#pragma unroll
        for (int kc = 0; kc < 8; ++kc) {
            int sofs = nrow + (((kc * 2 + h) ^ swzn) << 3);
            h8 xh = *(const h8*)&XH[sofs];
            h8 xl = *(const h8*)&XL[sofs];
            if (m == 2) {  // V: D[o][n] = W . X
                acc[g] = mfma32h(wf[kc], xh, acc[g]);
                acc[g] = mfma32h(wf[kc], xl, acc[g]);
            } else {  // Q/K: D[n][o] = X^T . W^T
                acc[g] = mfma32h(xh, wf[kc], acc[g]);
                acc[g] = mfma32h(xl, wf[kc], acc[g]);
            }
        }
    }

    if (m < 2) {  // D[n][o]: col=o (lane), rows=n; store [b][n][c], lanes coalesced in o
        float bval = bias[o0 + m32] * ((m == 0) ? LOG2E : 1.0f);
        hf* Y = ((m == 0) ? Qf : Kf) + (size_t)b * NPIX * CH;
#pragma unroll
        for (int g = 0; g < 2; ++g)
#pragma unroll
            for (int r = 0; r < 16; ++r) {
                int n = n0 + g * 32 + (r & 3) + 8 * (r >> 2) + 4 * h;
                Y[(size_t)n * CH + o0 + m32] = (hf)(acc[g][r] + bval);
            }
    } else {  // D[o][n]: col=n (lane), rows=o; store [b][c][n], lanes coalesced in n
        hf* Yv = Vf + (size_t)b * CH * NPIX;
#pragma unroll
        for (int g = 0; g < 2; ++g)
#pragma unroll
            for (int r = 0; r < 16; ++r) {
                int o = o0 + (r & 3) + 8 * (r >> 2) + 4 * h;
                Yv[(size_t)o * NPIX + n0 + g * 32 + m32] = (hf)(acc[g][r] + bias[o]);
            }
    }
}

// ---------------- fp16 MFMA flash attention, IN-BLOCK split-K (no combine kernel) --------
// grid: 8b * 64 q-tiles(64q) = 512 blocks = 2/CU. 4 waves = (qg x kh):
//   qg = w>>1 : which 32 queries;  kh = w&1 : which 2048-key half (separate stream).
// Each kh-pair streams its own key half through its own 2-buf pipeline:
//   LDS 64 KB = K[2 streams][2 bufs][8 KB] + V[2 streams][2 bufs][8 KB].
// Per iter: stage(t+1 -> freed buf) BEFORE waiting; WAITB(8) [own tile t landed,
//   t+1 stays in flight - never drains]; comp(t); BARB() [frees buf for t+2].
// Epilogue: cross-kh merge via LDS (R0's proven pattern) + direct fp32 out write.
__global__ __launch_bounds__(256, 2) void attn_kernel(const hf* __restrict__ Qf,
                                                      const hf* __restrict__ Kf,
                                                      const hf* __restrict__ Vf,
                                                      float* __restrict__ out) {
    __shared__ __align__(16) ushort_t smem[32768];  // 64 KB

    int tid = threadIdx.x;
    int lane = tid & 63;
    int w = tid >> 6;
    int h = lane >> 5;
    int m32 = lane & 31;
    int qg = w >> 1;  // query group (32 q)
    int kh = w & 1;   // key-half stream

    int idx = blockIdx.x;
    int b = idx & 7;             // batch <-> XCD (K/V stay L2-local)
    int qt = idx >> 3;           // query tile (64 q), 0..63
    int q0 = (qt << 6) + qg * 32;
    int k0g = kh << 11;          // this stream's 2048-key base

    const hf* Qb = Qf + (size_t)b * NPIX * CH;
    const hf* Kb = Kf + (size_t)b * NPIX * CH;
    const hf* Vb = Vf + (size_t)b * CH * NPIX;

    // Q B-frags (col = q0+m32), registers for whole loop
    h8 qf[8];
#pragma unroll
    for (int kc = 0; kc < 8; ++kc)
        qf[kc] = *(const h8*)&Qb[(size_t)(q0 + m32) * CH + kc * 16 + h * 8];

    // DMA source pointers (XOR swizzle folded into global address).
    // Stream tile: K [32 rows][128 ch] 8 KB (16 slots/row, slot ^ (row&15));
    //              V [128 ch][32 k]  8 KB (4 slots/row, slot ^ (c&3) ^ ((c>>2)&1)).
    // Each stream staged by its 2 waves (qg 0,1): chunk c8 = qg*4 + a, a 0..3.
    const hf* pK[4];
    const hf* pV[4];
#pragma unroll
    for (int a = 0; a < 4; ++a) {
        int c8 = qg * 4 + a;  // 0..7
        int rowk = c8 * 4 + (lane >> 4);                 // 0..31
        int lck = (lane & 15) ^ (rowk & 15);
        pK[a] = Kb + (size_t)(k0g + rowk) * CH + lck * 8;
        int rowv = c8 * 16 + (lane >> 2);                // 0..127 (= channel)
        int lcv = (lane & 3) ^ (rowv & 3) ^ ((rowv >> 2) & 1);
        pV[a] = Vb + (size_t)rowv * NPIX + k0g + lcv * 8;
    }

    f16v accO[4];
#pragma unroll
    for (int ct = 0; ct < 4; ++ct)
#pragma unroll
        for (int r = 0; r < 16; ++r) accO[ct][r] = 0.f;
    float mprev = -1e30f;  // per-query running max (base-2 units), this key-half
    float lsum = 0.f;      // per-lane-half partial sum (merged in epilogue)

    int pvs[2];
#pragma unroll
    for (int g2 = 0; g2 < 2; ++g2)
        pvs[g2] = (g2 * 2 + h) ^ (m32 & 3) ^ ((m32 >> 2) & 1);

    int kbase = (kh * 2) * 4096;          // this stream's K buf0 (ushort idx)
    int vbase = 16384 + (kh * 2) * 4096;  // this stream's V buf0

    // stage one 32-key tile into stream buffer buf (0/1), advance pointers
    auto stage = [&](int buf) {
#pragma unroll
        for (int a = 0; a < 4; ++a) {
            int c8 = qg * 4 + a;
            dma16(pK[a], &smem[kbase + buf * 4096 + c8 * 512]);
            dma16(pV[a], &smem[vbase + buf * 4096 + c8 * 512]);
            pK[a] += 32 * CH;
            pV[a] += 32;
        }
    };

    // compute one 32-key tile from stream buffer buf
    auto comp = [&](int buf) {
        const ushort_t* kb = smem + kbase + buf * 4096;
        const ushort_t* vb = smem + vbase + buf * 4096;

        // --- S^T[key][query] = K . Q^T (32 keys x this wave's 32 queries) ---
        f16v acc;
#pragma unroll
        for (int r = 0; r < 16; ++r) acc[r] = 0.f;
        __builtin_amdgcn_s_setprio(1);
#pragma unroll
        for (int kc = 0; kc < 8; ++kc) {
            int pA = (kc * 2 + h) ^ (m32 & 15);
            h8 ahi = *(const h8*)&kb[m32 * 128 + pA * 8];
            acc = mfma32h(ahi, qf[kc], acc);
        }
        __builtin_amdgcn_s_setprio(0);

        // --- wave-private online softmax (base-2 units, deferred max) ---
        float ta = fmaxf(fmaxf(acc[0], acc[1]), acc[2]);
        float tb = fmaxf(fmaxf(acc[3], acc[4]), acc[5]);
        ta = fmaxf(fmaxf(ta, acc[6]), acc[7]);
        tb = fmaxf(fmaxf(tb, acc[8]), acc[9]);
        ta = fmaxf(fmaxf(ta, acc[10]), acc[11]);
        tb = fmaxf(fmaxf(tb, acc[12]), acc[13]);
        ta = fmaxf(fmaxf(ta, acc[14]), acc[15]);
        float tmax = fmaxf(ta, tb);  // this lane-half's tile max
        if (__any(tmax > mprev + RESCALE_THR)) {
            float tx = fmaxf(tmax, __shfl_xor(tmax, 32));  // exact cross-half max
            float mnew = fmaxf(mprev, tx);
            float alpha = exp2f(mprev - mnew);
            lsum *= alpha;
#pragma unroll
            for (int ct = 0; ct < 4; ++ct)
#pragma unroll
                for (int r = 0; r < 16; ++r) accO[ct][r] *= alpha;
            mprev = mnew;
        }

        // exp2 + pack + per-lane-half row-sum (cross-half merge deferred)
        uint_t pk[8];
        float ps0 = 0.f, ps1 = 0.f;
#pragma unroll
        for (int t2 = 0; t2 < 8; ++t2) {
            float e0 = exp2f(acc[2 * t2] - mprev);
            float e1 = exp2f(acc[2 * t2 + 1] - mprev);
            ps0 += e0;
            ps1 += e1;
            pk[t2] = pk2h(e0, e1);
        }
        lsum += ps0 + ps1;

        // both-half P fragments via permlane32_swap
        pl32swap(pk[0], pk[2]);
        pl32swap(pk[1], pk[3]);
        pl32swap(pk[4], pk[6]);
        pl32swap(pk[5], pk[7]);
        h8 pbp[2];
#pragma unroll
        for (int g2 = 0; g2 < 2; ++g2) {
            u4 fv;
            fv[0] = pk[g2 * 4 + 0];
            fv[1] = pk[g2 * 4 + 1];
            fv[2] = pk[g2 * 4 + 2];
            fv[3] = pk[g2 * 4 + 3];
            __builtin_memcpy(&pbp[g2], &fv, 16);
        }

        // --- O^T[c][q] += V . P ---
        __builtin_amdgcn_s_setprio(1);
#pragma unroll
        for (int g2 = 0; g2 < 2; ++g2) {
            int pv = pvs[g2];
#pragma unroll
            for (int ct = 0; ct < 4; ++ct) {
                h8 av = *(const h8*)&vb[(ct * 32 + m32) * 32 + pv * 8];
                accO[ct] = mfma32h(av, pbp[g2], accO[ct]);
            }
        }
        __builtin_amdgcn_s_setprio(0);
    };

    // prologue: tile 0 -> buf 0
    stage(0);

    // main loop, 64 tiles per stream; stage(t+1) BEFORE the wait keeps 8 in flight
    for (int tb = 0; tb < 31; ++tb) {
        stage(1); WAITB(8); comp(0); BARB();
        stage(0); WAITB(8); comp(1); BARB();
    }
    stage(1); WAITB(8); comp(0); BARB();  // t=62, stages tile 63
    WAITB(0); comp(1);                    // t=63 (final drain)

    // --- epilogue: merge lane-halves, then merge the two key-half streams ---
    lsum += __shfl_xor(lsum, 32);

    __syncthreads();  // streaming done; LDS reusable
    float* scr = (float*)smem;   // [2kh][64q] M then [2kh][64q] L
    float* mrg = scr + 256;      // [128 ch][64 q] fp32 = 32 KB
    int q = qg * 32 + m32;
    if (h == 0) {
        scr[kh * 64 + q] = mprev;
        scr[128 + kh * 64 + q] = lsum;
    }
    __syncthreads();
    float mo = scr[(1 - kh) * 64 + q];
    float lo = scr[128 + (1 - kh) * 64 + q];
    float M = fmaxf(mprev, mo);
    float fk = exp2f(mprev - M);
    float fo = exp2f(mo - M);
    float rd = 1.0f / (fk * lsum + fo * lo);
    __syncthreads();  // scr read complete (mrg aliases beyond scr, but keep ordering)

    if (kh == 1) {
#pragma unroll
        for (int ct = 0; ct < 4; ++ct)
#pragma unroll
            for (int r = 0; r < 16; ++r) {
                int ch = ct * 32 + (r & 3) + 8 * (r >> 2) + 4 * h;
                mrg[ch * 64 + q] = accO[ct][r] * fk;
            }
    }
    __syncthreads();
    if (kh == 0) {
        float* O = out + (size_t)b * CH * NPIX + (qt << 6);
#pragma unroll
        for (int ct = 0; ct < 4; ++ct)
#pragma unroll
            for (int r = 0; r < 16; ++r) {
                int ch = ct * 32 + (r & 3) + 8 * (r >> 2) + 4 * h;
                O[(size_t)ch * NPIX + q] = (accO[ct][r] * fk + mrg[ch * 64 + q]) * rd;
            }
    }
}

extern "C" void kernel_launch(void* const* d_in, const int* in_sizes, int n_in,
                              void* d_out, int out_size, void* d_ws, size_t ws_size,
                              hipStream_t stream) {
    const float* x1 = (const float*)d_in[0];
    const float* x2 = (const float*)d_in[1];
    const float* Wq = (const float*)d_in[2];
    const float* bq = (const float*)d_in[3];
    const float* Wk = (const float*)d_in[4];
    const float* bk = (const float*)d_in[5];
    const float* Wv = (const float*)d_in[6];
    const float* bv = (const float*)d_in[7];
    float* outp = (float*)d_out;

    const size_t N = (size_t)BATCH * NPIX * CH;  // 4.19M
    hf* Qf = (hf*)d_ws;
    hf* Kf = Qf + N;
    hf* Vf = Qf + 2 * N;

    qkv_kernel<<<3 * BATCH * (NPIX / 64), 256, 0, stream>>>(x1, x2, Wq, Wk, Wv,
                                                            bq, bk, bv, Qf, Kf, Vf);
    attn_kernel<<<BATCH * (NPIX / 64), 256, 0, stream>>>(Qf, Kf, Vf, outp);
}